// Round 1
// baseline (1346.805 us; speedup 1.0000x reference)
//
#include <hip/hip_runtime.h>

#define EMBED 1024
#define NHEADS 16
#define HDIM 64
#define SEQ 2048
#define BATCH 2
#define MROWS (BATCH * SEQ)   // 4096

// ---------------------------------------------------------------------------
// Tiled fp32 GEMM with bias: C[m][n] = sum_k A[m][k] * W[k][n] + bias[n]
// transposed_write==0: out is row-major [MROWS x EMBED]
// transposed_write==1: out[((b*NHEADS+h)*SEQ + t)*HDIM + d]  (head-major QKV)
// Block: 256 threads, 64x64 output tile, 4x4 register micro-tile, BK=16.
// ---------------------------------------------------------------------------
__global__ __launch_bounds__(256)
void gemm_bias_kernel(const float* __restrict__ A, const float* __restrict__ W,
                      const float* __restrict__ bias, float* __restrict__ out,
                      int transposed_write)
{
    __shared__ float As[16][68];   // [k][m], pad to 68 (16B-aligned rows, 2-way banks only)
    __shared__ float Bs[16][68];   // [k][n]

    const int tid = threadIdx.x;
    const int bm = blockIdx.y * 64;
    const int bn = blockIdx.x * 64;
    const int tr = tid >> 4;           // 0..15 (row group)
    const int tc = tid & 15;           // 0..15 (col group)
    const int la_r = tid >> 2;         // 0..63 A-tile row
    const int la_k = (tid & 3) << 2;   // 0,4,8,12
    const int lb_k = tid >> 4;         // 0..15 B-tile k
    const int lb_n = (tid & 15) << 2;  // 0..60

    float acc[4][4];
#pragma unroll
    for (int i = 0; i < 4; ++i)
#pragma unroll
        for (int j = 0; j < 4; ++j) acc[i][j] = 0.f;

    for (int k0 = 0; k0 < EMBED; k0 += 16) {
        float4 av = *(const float4*)(A + (size_t)(bm + la_r) * EMBED + k0 + la_k);
        As[la_k + 0][la_r] = av.x;
        As[la_k + 1][la_r] = av.y;
        As[la_k + 2][la_r] = av.z;
        As[la_k + 3][la_r] = av.w;
        *(float4*)(&Bs[lb_k][lb_n]) =
            *(const float4*)(W + (size_t)(k0 + lb_k) * EMBED + bn + lb_n);
        __syncthreads();
#pragma unroll
        for (int kk = 0; kk < 16; ++kk) {
            float4 a = *(const float4*)(&As[kk][tr << 2]);
            float4 b = *(const float4*)(&Bs[kk][tc << 2]);
            float ar[4] = {a.x, a.y, a.z, a.w};
            float br[4] = {b.x, b.y, b.z, b.w};
#pragma unroll
            for (int i = 0; i < 4; ++i)
#pragma unroll
                for (int j = 0; j < 4; ++j) acc[i][j] += ar[i] * br[j];
        }
        __syncthreads();
    }

    float bv[4];
#pragma unroll
    for (int j = 0; j < 4; ++j) bv[j] = bias[bn + (tc << 2) + j];

    if (!transposed_write) {
#pragma unroll
        for (int i = 0; i < 4; ++i) {
            int m = bm + (tr << 2) + i;
            float4 v = make_float4(acc[i][0] + bv[0], acc[i][1] + bv[1],
                                   acc[i][2] + bv[2], acc[i][3] + bv[3]);
            *(float4*)(out + (size_t)m * EMBED + bn + (tc << 2)) = v;
        }
    } else {
        const int h = bn >> 6;        // head index (BN==HDIM==64)
        const int d = tc << 2;        // 0..60
#pragma unroll
        for (int i = 0; i < 4; ++i) {
            int m = bm + (tr << 2) + i;
            int b = m >> 11;          // /SEQ
            int t = m & (SEQ - 1);
            float4 v = make_float4(acc[i][0] + bv[0], acc[i][1] + bv[1],
                                   acc[i][2] + bv[2], acc[i][3] + bv[3]);
            *(float4*)(out + (((size_t)(b * NHEADS + h) * SEQ + t) << 6) + d) = v;
        }
    }
}

// ---------------------------------------------------------------------------
// Flash-style causal attention, fp32. One block = one (b,h) x 32-query tile.
// 256 threads: row r = tid/8 (32 rows), col-group cg = tid%8.
// Online softmax state (m,l) replicated across the 8 lanes of a row
// (identical via width-8 shuffle reductions). O accumulator in registers:
// 8 floats/thread = cols cg*8..cg*8+7 of row r.
// ---------------------------------------------------------------------------
__global__ __launch_bounds__(256)
void attn_kernel(const float* __restrict__ Q, const float* __restrict__ K,
                 const float* __restrict__ V, float* __restrict__ Oout)
{
    __shared__ float Qs[32][68];
    __shared__ float Ks[32][68];
    __shared__ float Vs[32][68];
    __shared__ float Ps[32][36];

    const int tid = threadIdx.x;
    const int bh = blockIdx.y;            // 0..31 = b*NHEADS + h
    const int q0 = blockIdx.x << 5;       // query tile base
    const int r  = tid >> 3;              // 0..31
    const int cg = tid & 7;               // 0..7
    const size_t base = (size_t)bh * SEQ * HDIM;

    // load + scale Q tile (fully coalesced: addr = base + tid*8)
    {
        const float* src = Q + base + ((size_t)q0 << 6);
        int row = tid >> 3;
        int col = (tid & 7) << 3;
        float4 v0 = *(const float4*)(src + (row << 6) + col);
        float4 v1 = *(const float4*)(src + (row << 6) + col + 4);
        const float sc = 0.125f;          // 1/sqrt(64)
        Qs[row][col + 0] = v0.x * sc; Qs[row][col + 1] = v0.y * sc;
        Qs[row][col + 2] = v0.z * sc; Qs[row][col + 3] = v0.w * sc;
        Qs[row][col + 4] = v1.x * sc; Qs[row][col + 5] = v1.y * sc;
        Qs[row][col + 6] = v1.z * sc; Qs[row][col + 7] = v1.w * sc;
    }

    float m_i = -1e30f, l_i = 0.f;
    float o_acc[8];
#pragma unroll
    for (int c = 0; c < 8; ++c) o_acc[c] = 0.f;

    const int qi = q0 + r;
    const int jbase = cg << 2;
    const int c0 = cg << 3;
    const int ktmax = q0 >> 5;

    for (int kt = 0; kt <= ktmax; ++kt) {
        const int k0 = kt << 5;
        __syncthreads();  // prev iter's PV reads done before K/V overwrite
        {
            const float* srcK = K + base + ((size_t)k0 << 6);
            const float* srcV = V + base + ((size_t)k0 << 6);
            int row = tid >> 3;
            int col = (tid & 7) << 3;
            *(float4*)(&Ks[row][col])     = *(const float4*)(srcK + (row << 6) + col);
            *(float4*)(&Ks[row][col + 4]) = *(const float4*)(srcK + (row << 6) + col + 4);
            *(float4*)(&Vs[row][col])     = *(const float4*)(srcV + (row << 6) + col);
            *(float4*)(&Vs[row][col + 4]) = *(const float4*)(srcV + (row << 6) + col + 4);
        }
        __syncthreads();

        // S = Qs @ Ks^T for this thread's 4 columns
        float s[4] = {0.f, 0.f, 0.f, 0.f};
#pragma unroll
        for (int d = 0; d < 64; d += 4) {
            float4 qv = *(const float4*)(&Qs[r][d]);
#pragma unroll
            for (int jj = 0; jj < 4; ++jj) {
                float4 kv = *(const float4*)(&Ks[jbase + jj][d]);
                s[jj] += qv.x * kv.x + qv.y * kv.y + qv.z * kv.z + qv.w * kv.w;
            }
        }
        // causal mask
#pragma unroll
        for (int jj = 0; jj < 4; ++jj)
            if (k0 + jbase + jj > qi) s[jj] = -1e30f;

        // online softmax
        float mx = fmaxf(fmaxf(s[0], s[1]), fmaxf(s[2], s[3]));
        mx = fmaxf(mx, __shfl_xor(mx, 1));
        mx = fmaxf(mx, __shfl_xor(mx, 2));
        mx = fmaxf(mx, __shfl_xor(mx, 4));
        float newm = fmaxf(m_i, mx);
        float alpha = __expf(m_i - newm);
        float p[4], psum = 0.f;
#pragma unroll
        for (int jj = 0; jj < 4; ++jj) { p[jj] = __expf(s[jj] - newm); psum += p[jj]; }
        psum += __shfl_xor(psum, 1);
        psum += __shfl_xor(psum, 2);
        psum += __shfl_xor(psum, 4);
        l_i = l_i * alpha + psum;
        m_i = newm;
#pragma unroll
        for (int c = 0; c < 8; ++c) o_acc[c] *= alpha;
        Ps[r][jbase + 0] = p[0]; Ps[r][jbase + 1] = p[1];
        Ps[r][jbase + 2] = p[2]; Ps[r][jbase + 3] = p[3];
        __syncthreads();

        // O += P @ V
#pragma unroll
        for (int j = 0; j < 32; ++j) {
            float pj = Ps[r][j];
            float4 v0 = *(const float4*)(&Vs[j][c0]);
            float4 v1 = *(const float4*)(&Vs[j][c0 + 4]);
            o_acc[0] += pj * v0.x; o_acc[1] += pj * v0.y;
            o_acc[2] += pj * v0.z; o_acc[3] += pj * v0.w;
            o_acc[4] += pj * v1.x; o_acc[5] += pj * v1.y;
            o_acc[6] += pj * v1.z; o_acc[7] += pj * v1.w;
        }
    }

    // epilogue: normalize, write to [B, T, EMBED] with head offset
    float inv = 1.f / l_i;
    int b = bh >> 4;          // / NHEADS
    int h = bh & 15;
    float* dst = Oout + ((size_t)(b * SEQ + q0 + r) * EMBED) + h * HDIM + c0;
    float4 w0 = make_float4(o_acc[0] * inv, o_acc[1] * inv, o_acc[2] * inv, o_acc[3] * inv);
    float4 w1 = make_float4(o_acc[4] * inv, o_acc[5] * inv, o_acc[6] * inv, o_acc[7] * inv);
    *(float4*)dst = w0;
    *(float4*)(dst + 4) = w1;
}

extern "C" void kernel_launch(void* const* d_in, const int* in_sizes, int n_in,
                              void* d_out, int out_size, void* d_ws, size_t ws_size,
                              hipStream_t stream) {
    const float* x  = (const float*)d_in[0];
    const float* Wq = (const float*)d_in[1];
    const float* bq = (const float*)d_in[2];
    const float* Wk = (const float*)d_in[3];
    const float* bk = (const float*)d_in[4];
    const float* Wv = (const float*)d_in[5];
    const float* bv = (const float*)d_in[6];
    const float* Wo = (const float*)d_in[7];
    const float* bo = (const float*)d_in[8];
    float* out = (float*)d_out;

    float* ws = (float*)d_ws;
    const size_t SZ = (size_t)MROWS * EMBED;  // 4M floats
    float* q  = ws;
    float* k  = ws + SZ;
    float* v  = ws + 2 * SZ;
    float* ao = ws + 3 * SZ;

    dim3 gg(EMBED / 64, MROWS / 64);   // (16, 64)
    gemm_bias_kernel<<<gg, 256, 0, stream>>>(x, Wq, bq, q, 1);
    gemm_bias_kernel<<<gg, 256, 0, stream>>>(x, Wk, bk, k, 1);
    gemm_bias_kernel<<<gg, 256, 0, stream>>>(x, Wv, bv, v, 1);

    dim3 ga(SEQ / 32, BATCH * NHEADS); // (64, 32)
    attn_kernel<<<ga, 256, 0, stream>>>(q, k, v, ao);

    gemm_bias_kernel<<<gg, 256, 0, stream>>>(ao, Wo, bo, out, 0);
}

// Round 2
// 633.274 us; speedup vs baseline: 2.1267x; 2.1267x over previous
//
#include <hip/hip_runtime.h>

#define EMBED 1024
#define NHEADS 16
#define HDIM 64
#define SEQ 2048
#define BATCH 2
#define MROWS (BATCH * SEQ)   // 4096

using bf16x8 = __attribute__((ext_vector_type(8))) short;
using f32x4  = __attribute__((ext_vector_type(4))) float;
using us4    = __attribute__((ext_vector_type(4))) unsigned short;

__device__ __forceinline__ unsigned short f2bf(float f) {
    unsigned int u = __builtin_bit_cast(unsigned int, f);
    u = (u + 0x7fffu + ((u >> 16) & 1u)) >> 16;   // RNE
    return (unsigned short)u;
}

// ---------------------------------------------------------------------------
// Tiled fp32 GEMM with bias: C[m][n] = sum_k A[m][k] * W[k][n] + bias[n]
// mode 0: fp32 out, row-major [MROWS x EMBED]
// mode 1: bf16 out, per-head [bh][t][d], scaled by 0.125*log2(e)  (Q)
// mode 2: bf16 out, per-head [bh][t][d]                            (K)
// mode 3: bf16 out, per-head TRANSPOSED [bh][d][t]                 (V^T)
// ---------------------------------------------------------------------------
__global__ __launch_bounds__(256)
void gemm_bias_kernel(const float* __restrict__ A, const float* __restrict__ W,
                      const float* __restrict__ bias, void* __restrict__ outv,
                      int mode)
{
    __shared__ float As[16][68];
    __shared__ float Bs[16][68];

    const int tid = threadIdx.x;
    const int bm = blockIdx.y * 64;
    const int bn = blockIdx.x * 64;
    const int tr = tid >> 4;
    const int tc = tid & 15;
    const int la_r = tid >> 2;
    const int la_k = (tid & 3) << 2;
    const int lb_k = tid >> 4;
    const int lb_n = (tid & 15) << 2;

    float acc[4][4];
#pragma unroll
    for (int i = 0; i < 4; ++i)
#pragma unroll
        for (int j = 0; j < 4; ++j) acc[i][j] = 0.f;

    for (int k0 = 0; k0 < EMBED; k0 += 16) {
        float4 av = *(const float4*)(A + (size_t)(bm + la_r) * EMBED + k0 + la_k);
        As[la_k + 0][la_r] = av.x;
        As[la_k + 1][la_r] = av.y;
        As[la_k + 2][la_r] = av.z;
        As[la_k + 3][la_r] = av.w;
        *(float4*)(&Bs[lb_k][lb_n]) =
            *(const float4*)(W + (size_t)(k0 + lb_k) * EMBED + bn + lb_n);
        __syncthreads();
#pragma unroll
        for (int kk = 0; kk < 16; ++kk) {
            float4 a = *(const float4*)(&As[kk][tr << 2]);
            float4 b = *(const float4*)(&Bs[kk][tc << 2]);
            float ar[4] = {a.x, a.y, a.z, a.w};
            float br[4] = {b.x, b.y, b.z, b.w};
#pragma unroll
            for (int i = 0; i < 4; ++i)
#pragma unroll
                for (int j = 0; j < 4; ++j) acc[i][j] += ar[i] * br[j];
        }
        __syncthreads();
    }

    float bv[4];
#pragma unroll
    for (int j = 0; j < 4; ++j) bv[j] = bias[bn + (tc << 2) + j];

    if (mode == 0) {
        float* out = (float*)outv;
#pragma unroll
        for (int i = 0; i < 4; ++i) {
            int m = bm + (tr << 2) + i;
            float4 v = make_float4(acc[i][0] + bv[0], acc[i][1] + bv[1],
                                   acc[i][2] + bv[2], acc[i][3] + bv[3]);
            *(float4*)(out + (size_t)m * EMBED + bn + (tc << 2)) = v;
        }
    } else if (mode == 3) {
        // V^T: out[((b*16+h)*64 + d)*2048 + t], bf16
        unsigned short* out = (unsigned short*)outv;
        const int h = bn >> 6;
#pragma unroll
        for (int i = 0; i < 4; ++i) {
            int m = bm + (tr << 2) + i;
            int b = m >> 11;
            int t = m & (SEQ - 1);
#pragma unroll
            for (int j = 0; j < 4; ++j) {
                int dl = (bn & 63) + (tc << 2) + j;
                out[(((size_t)(b * NHEADS + h) << 6) + dl) * SEQ + t] =
                    f2bf(acc[i][j] + bv[j]);
            }
        }
    } else {
        // Q/K: out[((b*16+h)*2048 + t)*64 + d], bf16, Q pre-scaled
        const float scale = (mode == 1) ? 0.125f * 1.4426950408889634f : 1.0f;
        unsigned short* out = (unsigned short*)outv;
        const int h = bn >> 6;
        const int d0 = (tc << 2);
#pragma unroll
        for (int i = 0; i < 4; ++i) {
            int m = bm + (tr << 2) + i;
            int b = m >> 11;
            int t = m & (SEQ - 1);
            us4 v;
#pragma unroll
            for (int j = 0; j < 4; ++j) v[j] = f2bf((acc[i][j] + bv[j]) * scale);
            *(us4*)(out + ((((size_t)(b * NHEADS + h) << 11) + t) << 6) + d0) = v;
        }
    }
}

// ---------------------------------------------------------------------------
// bf16 MFMA flash attention. Block = 256 thr (4 waves). Each block handles
// TWO 64-row q-tiles {31-bx, bx} (perfect balance: 33 key-tiles total).
// Wave w owns q rows [q0+16w, q0+16w+16). Key-tile = 64.
// MFMA 16x16x32_bf16 layouts: A[m=lane&15][k=quad*8+j]; B[k=quad*8+j][n=lane&15];
// D[m=quad*4+reg][n=lane&15]. Q pre-scaled by 0.125*log2e -> exp2 softmax.
// LDS row stride 72 bf16 (144B, 16B-aligned, bank-uniform b128 fragments).
// ---------------------------------------------------------------------------
__global__ __launch_bounds__(256)
void attn_mfma(const unsigned short* __restrict__ Qb,
               const unsigned short* __restrict__ Kb,
               const unsigned short* __restrict__ Vtb,
               float* __restrict__ Oout)
{
    __shared__ unsigned short Ks[64 * 72];      // [key][d]
    __shared__ unsigned short Vt[64 * 72];      // [d][key]
    __shared__ unsigned short Ps[4][16 * 72];   // per-wave [m][key]

    const int tid  = threadIdx.x;
    const int wv   = tid >> 6;
    const int lane = tid & 63;
    const int m16  = lane & 15;
    const int quad = lane >> 4;
    const int bh   = blockIdx.y;
    const int b    = bh >> 4, h = bh & 15;

    const int srow = tid >> 2;         // 0..63
    const int scol = (tid & 3) << 4;   // 0,16,32,48

    for (int phase = 0; phase < 2; ++phase) {
        const int qt = phase == 0 ? (31 - (int)blockIdx.x) : (int)blockIdx.x;
        const int q0 = qt << 6;

        const size_t qoff =
            (((size_t)bh << 11) + q0 + (wv << 4) + m16) * 64 + (quad << 3);
        bf16x8 qa0 = *(const bf16x8*)(Qb + qoff);
        bf16x8 qa1 = *(const bf16x8*)(Qb + qoff + 32);

        f32x4 o[4];
        float m_[4], l_[4];
#pragma unroll
        for (int dt = 0; dt < 4; ++dt) o[dt] = (f32x4){0.f, 0.f, 0.f, 0.f};
#pragma unroll
        for (int r = 0; r < 4; ++r) { m_[r] = -1e30f; l_[r] = 0.f; }

        for (int kt = 0; kt <= qt; ++kt) {
            const int k0 = kt << 6;
            __syncthreads();
            {
                const unsigned short* sk =
                    Kb + (((size_t)bh << 11) + k0 + srow) * 64 + scol;
                *(bf16x8*)(Ks + srow * 72 + scol)     = *(const bf16x8*)(sk);
                *(bf16x8*)(Ks + srow * 72 + scol + 8) = *(const bf16x8*)(sk + 8);
                const unsigned short* sv =
                    Vtb + (((size_t)bh << 6) + srow) * SEQ + k0 + scol;
                *(bf16x8*)(Vt + srow * 72 + scol)     = *(const bf16x8*)(sv);
                *(bf16x8*)(Vt + srow * 72 + scol + 8) = *(const bf16x8*)(sv + 8);
            }
            __syncthreads();

            // S = Q K^T (in log2 domain; Q pre-scaled)
            f32x4 s[4];
#pragma unroll
            for (int g = 0; g < 4; ++g) {
                s[g] = (f32x4){0.f, 0.f, 0.f, 0.f};
                const unsigned short* kp = Ks + (g * 16 + m16) * 72 + (quad << 3);
                bf16x8 kb0 = *(const bf16x8*)kp;
                bf16x8 kb1 = *(const bf16x8*)(kp + 32);
                s[g] = __builtin_amdgcn_mfma_f32_16x16x32_bf16(qa0, kb0, s[g], 0, 0, 0);
                s[g] = __builtin_amdgcn_mfma_f32_16x16x32_bf16(qa1, kb1, s[g], 0, 0, 0);
            }

            if (kt == qt) {   // diagonal tile: causal mask
#pragma unroll
                for (int g = 0; g < 4; ++g) {
                    int thr = g * 16 + m16 - wv * 16 - quad * 4;  // masked if r < thr
#pragma unroll
                    for (int r = 0; r < 4; ++r)
                        if (r < thr) s[g][r] = -1e30f;
                }
            }

            // online softmax (exp2 domain), stats per row r, reduce over 16 lanes
            float al[4];
#pragma unroll
            for (int r = 0; r < 4; ++r) {
                float v = fmaxf(fmaxf(s[0][r], s[1][r]), fmaxf(s[2][r], s[3][r]));
                v = fmaxf(v, __shfl_xor(v, 1));
                v = fmaxf(v, __shfl_xor(v, 2));
                v = fmaxf(v, __shfl_xor(v, 4));
                v = fmaxf(v, __shfl_xor(v, 8));
                float nm = fmaxf(m_[r], v);
                al[r] = exp2f(m_[r] - nm);
                float sum = 0.f;
#pragma unroll
                for (int g = 0; g < 4; ++g) {
                    float p = exp2f(s[g][r] - nm);
                    s[g][r] = p;
                    sum += p;
                }
                sum += __shfl_xor(sum, 1);
                sum += __shfl_xor(sum, 2);
                sum += __shfl_xor(sum, 4);
                sum += __shfl_xor(sum, 8);
                l_[r] = l_[r] * al[r] + sum;
                m_[r] = nm;
            }

            // P -> LDS (bf16, A-operand ready); wave-local, no barrier needed
#pragma unroll
            for (int g = 0; g < 4; ++g)
#pragma unroll
                for (int r = 0; r < 4; ++r)
                    Ps[wv][(quad * 4 + r) * 72 + g * 16 + m16] = f2bf(s[g][r]);

#pragma unroll
            for (int dt = 0; dt < 4; ++dt)
#pragma unroll
                for (int r = 0; r < 4; ++r) o[dt][r] *= al[r];

            const unsigned short* pp = &Ps[wv][m16 * 72 + (quad << 3)];
            bf16x8 pa0 = *(const bf16x8*)pp;
            bf16x8 pa1 = *(const bf16x8*)(pp + 32);
#pragma unroll
            for (int dt = 0; dt < 4; ++dt) {
                const unsigned short* vp = Vt + (dt * 16 + m16) * 72 + (quad << 3);
                bf16x8 vb0 = *(const bf16x8*)vp;
                bf16x8 vb1 = *(const bf16x8*)(vp + 32);
                o[dt] = __builtin_amdgcn_mfma_f32_16x16x32_bf16(pa0, vb0, o[dt], 0, 0, 0);
                o[dt] = __builtin_amdgcn_mfma_f32_16x16x32_bf16(pa1, vb1, o[dt], 0, 0, 0);
            }
        }

        // epilogue: normalize + write fp32 [b*T+t][1024] at head offset
        float inv[4];
#pragma unroll
        for (int r = 0; r < 4; ++r) inv[r] = 1.f / l_[r];
        const int trow = q0 + (wv << 4) + quad * 4;
#pragma unroll
        for (int dt = 0; dt < 4; ++dt)
#pragma unroll
            for (int r = 0; r < 4; ++r)
                Oout[((size_t)((b << 11) + trow + r) << 10) + (h << 6) + dt * 16 + m16] =
                    o[dt][r] * inv[r];
    }
}

extern "C" void kernel_launch(void* const* d_in, const int* in_sizes, int n_in,
                              void* d_out, int out_size, void* d_ws, size_t ws_size,
                              hipStream_t stream) {
    const float* x  = (const float*)d_in[0];
    const float* Wq = (const float*)d_in[1];
    const float* bq = (const float*)d_in[2];
    const float* Wk = (const float*)d_in[3];
    const float* bk = (const float*)d_in[4];
    const float* Wv = (const float*)d_in[5];
    const float* bv = (const float*)d_in[6];
    const float* Wo = (const float*)d_in[7];
    const float* bo = (const float*)d_in[8];
    float* out = (float*)d_out;

    const size_t HSZ = (size_t)BATCH * NHEADS * SEQ * HDIM;  // 4M elems
    unsigned short* qb  = (unsigned short*)d_ws;
    unsigned short* kb  = qb + HSZ;
    unsigned short* vtb = kb + HSZ;
    float* ao = (float*)(vtb + HSZ);

    dim3 gg(EMBED / 64, MROWS / 64);   // (16, 64)
    gemm_bias_kernel<<<gg, 256, 0, stream>>>(x, Wq, bq, qb, 1);
    gemm_bias_kernel<<<gg, 256, 0, stream>>>(x, Wk, bk, kb, 2);
    gemm_bias_kernel<<<gg, 256, 0, stream>>>(x, Wv, bv, vtb, 3);

    dim3 ga(16, BATCH * NHEADS);       // paired q-tiles, 512 blocks
    attn_mfma<<<ga, 256, 0, stream>>>(qb, kb, vtb, ao);

    gemm_bias_kernel<<<gg, 256, 0, stream>>>(ao, Wo, bo, out, 0);
}

// Round 3
// 251.580 us; speedup vs baseline: 5.3534x; 2.5172x over previous
//
#include <hip/hip_runtime.h>

#define EMBED 1024
#define NHEADS 16
#define HDIM 64
#define SEQ 2048
#define BATCH 2
#define MROWS (BATCH * SEQ)   // 4096

using bf16x8 = __attribute__((ext_vector_type(8))) short;
using f32x4  = __attribute__((ext_vector_type(4))) float;
using us4    = __attribute__((ext_vector_type(4))) unsigned short;

__device__ __forceinline__ unsigned short f2bf(float f) {
    unsigned int u = __builtin_bit_cast(unsigned int, f);
    u = (u + 0x7fffu + ((u >> 16) & 1u)) >> 16;   // RNE
    return (unsigned short)u;
}

__device__ __forceinline__ void async16(const unsigned short* g, unsigned short* l) {
    __builtin_amdgcn_global_load_lds(
        (const __attribute__((address_space(1))) void*)g,
        (__attribute__((address_space(3))) void*)l, 16, 0, 0);
}

// ---------------------------------------------------------------------------
// convert x (fp32 [4096][1024]) -> bf16, 4 elems/thread
// ---------------------------------------------------------------------------
__global__ __launch_bounds__(256)
void cvt_x(const float* __restrict__ in, unsigned short* __restrict__ out)
{
    int i = blockIdx.x * 256 + threadIdx.x;          // 1M threads
    float4 v = ((const float4*)in)[i];
    us4 o;
    o[0] = f2bf(v.x); o[1] = f2bf(v.y); o[2] = f2bf(v.z); o[3] = f2bf(v.w);
    ((us4*)out)[i] = o;
}

// ---------------------------------------------------------------------------
// convert + transpose weights: W fp32 [k][n] -> Wt bf16 [n][k]. 64x64 tiles.
// ---------------------------------------------------------------------------
__global__ __launch_bounds__(256)
void cvt_w(const float* __restrict__ W0, const float* __restrict__ W1,
           const float* __restrict__ W2, const float* __restrict__ W3,
           unsigned short* __restrict__ T0, unsigned short* __restrict__ T1,
           unsigned short* __restrict__ T2, unsigned short* __restrict__ T3)
{
    const float* W = blockIdx.z == 0 ? W0 : blockIdx.z == 1 ? W1 :
                     blockIdx.z == 2 ? W2 : W3;
    unsigned short* T = blockIdx.z == 0 ? T0 : blockIdx.z == 1 ? T1 :
                        blockIdx.z == 2 ? T2 : T3;
    __shared__ unsigned short tile[64][72];
    const int tid = threadIdx.x;
    const int k0 = blockIdx.y << 6, n0 = blockIdx.x << 6;
    const int lr = tid >> 4, lc = (tid & 15) << 2;
#pragma unroll
    for (int it = 0; it < 4; ++it) {
        int kr = lr + it * 16;
        float4 v = *(const float4*)(W + (size_t)(k0 + kr) * EMBED + n0 + lc);
        tile[lc + 0][kr] = f2bf(v.x);
        tile[lc + 1][kr] = f2bf(v.y);
        tile[lc + 2][kr] = f2bf(v.z);
        tile[lc + 3][kr] = f2bf(v.w);
    }
    __syncthreads();
#pragma unroll
    for (int it = 0; it < 4; ++it) {
        int nr = lr + it * 16;
        us4 o = *(const us4*)(&tile[nr][lc]);
        *(us4*)(T + (size_t)(n0 + nr) * EMBED + k0 + lc) = o;
    }
}

// ---------------------------------------------------------------------------
// MFMA GEMM core: C(128x128) += A[4096][1024]row-tile @ Bt[n][k]^T tile.
// 256 thr / 4 waves (2x2 of 64x64). BK=64, global_load_lds width-16 staging.
// acc[i][j]: D[m = bm + (wv>>1)*64 + i*16 + quad*4 + r][n = n0 + (wv&1)*64 + j*16 + m16]
// ---------------------------------------------------------------------------
__device__ __forceinline__ void mfma_gemm_core(
    const unsigned short* __restrict__ A, const unsigned short* __restrict__ Bt,
    int bm, int n0, unsigned short* As, unsigned short* Bs,
    int wv, int lane, f32x4 acc[4][4])
{
    const int m16 = lane & 15, quad = lane >> 4;
    const int mb = (wv >> 1) << 6;
    const int nb = (wv & 1) << 6;

    const unsigned short* ga = A  + (size_t)(bm + wv * 32 + (lane >> 3)) * EMBED + ((lane & 7) << 3);
    const unsigned short* gb = Bt + (size_t)(n0 + wv * 32 + (lane >> 3)) * EMBED + ((lane & 7) << 3);
    unsigned short* la = As + wv * 32 * 64;
    unsigned short* lb = Bs + wv * 32 * 64;

    for (int k0 = 0; k0 < EMBED; k0 += 64) {
        __syncthreads();
#pragma unroll
        for (int j = 0; j < 4; ++j) {
            async16(ga + j * 8 * EMBED, la + j * 8 * 64);
            async16(gb + j * 8 * EMBED, lb + j * 8 * 64);
        }
        ga += 64; gb += 64;
        __syncthreads();
#pragma unroll
        for (int ks = 0; ks < 2; ++ks) {
            const int ko = ks * 32 + (quad << 3);
            bf16x8 af[4], bf[4];
#pragma unroll
            for (int i = 0; i < 4; ++i) {
                af[i] = *(const bf16x8*)(As + (mb + i * 16 + m16) * 64 + ko);
                bf[i] = *(const bf16x8*)(Bs + (nb + i * 16 + m16) * 64 + ko);
            }
#pragma unroll
            for (int i = 0; i < 4; ++i)
#pragma unroll
                for (int j = 0; j < 4; ++j)
                    acc[i][j] = __builtin_amdgcn_mfma_f32_16x16x32_bf16(
                        af[i], bf[j], acc[i][j], 0, 0, 0);
        }
    }
}

// ---------------------------------------------------------------------------
// Fused QKV projection. grid (24, 32): bx>>3 selects {Q,K,V}, (bx&7)*128 = n0.
// Epilogue: Q bf16 head-major scaled by 0.125*log2e; K bf16 head-major;
// V^T bf16 [bh][d][t] (us4-packed along t).
// ---------------------------------------------------------------------------
__global__ __launch_bounds__(256)
void qkv_gemm(const unsigned short* __restrict__ xb,
              const unsigned short* __restrict__ Wtq,
              const unsigned short* __restrict__ Wtk,
              const unsigned short* __restrict__ Wtv,
              const float* __restrict__ bq, const float* __restrict__ bk,
              const float* __restrict__ bv,
              unsigned short* __restrict__ Qo, unsigned short* __restrict__ Ko,
              unsigned short* __restrict__ Vto)
{
    __shared__ __align__(16) unsigned short As[128 * 64];
    __shared__ __align__(16) unsigned short Bs[128 * 64];
    const int tid = threadIdx.x, wv = tid >> 6, lane = tid & 63;
    const int m16 = lane & 15, quad = lane >> 4;
    const int which = blockIdx.x >> 3;
    const int n0 = (blockIdx.x & 7) << 7;
    const int bm = blockIdx.y << 7;
    const unsigned short* Bt = which == 0 ? Wtq : which == 1 ? Wtk : Wtv;
    const float* bias = which == 0 ? bq : which == 1 ? bk : bv;

    f32x4 acc[4][4];
#pragma unroll
    for (int i = 0; i < 4; ++i)
#pragma unroll
        for (int j = 0; j < 4; ++j) acc[i][j] = (f32x4){0.f, 0.f, 0.f, 0.f};

    mfma_gemm_core(xb, Bt, bm, n0, As, Bs, wv, lane, acc);

    const int mb = (wv >> 1) << 6, nb = (wv & 1) << 6;
    const float qscale = 0.125f * 1.4426950408889634f;
#pragma unroll
    for (int i = 0; i < 4; ++i) {
        const int m0 = bm + mb + i * 16 + quad * 4;
        const int b = m0 >> 11, t0 = m0 & (SEQ - 1);
#pragma unroll
        for (int j = 0; j < 4; ++j) {
            const int n = n0 + nb + j * 16 + m16;
            const int h = n >> 6, d = n & 63;
            const float bval = bias[n];
            if (which == 2) {
                us4 v;
#pragma unroll
                for (int r = 0; r < 4; ++r) v[r] = f2bf(acc[i][j][r] + bval);
                *(us4*)(Vto + ((((size_t)(b * NHEADS + h)) << 6) + d) * SEQ + t0) = v;
            } else {
                const float sc = which == 0 ? qscale : 1.f;
                unsigned short* dst = (which == 0 ? Qo : Ko) +
                    ((((size_t)(b * NHEADS + h)) << 11) + t0) * 64 + d;
#pragma unroll
                for (int r = 0; r < 4; ++r)
                    dst[(size_t)r * 64] = f2bf((acc[i][j][r] + bval) * sc);
            }
        }
    }
}

// ---------------------------------------------------------------------------
// Output projection: out fp32 [4096][1024] = ao_bf16 @ Wo + bo
// ---------------------------------------------------------------------------
__global__ __launch_bounds__(256)
void out_gemm(const unsigned short* __restrict__ aob,
              const unsigned short* __restrict__ Wto,
              const float* __restrict__ bo, float* __restrict__ out)
{
    __shared__ __align__(16) unsigned short As[128 * 64];
    __shared__ __align__(16) unsigned short Bs[128 * 64];
    const int tid = threadIdx.x, wv = tid >> 6, lane = tid & 63;
    const int m16 = lane & 15, quad = lane >> 4;
    const int n0 = blockIdx.x << 7;
    const int bm = blockIdx.y << 7;

    f32x4 acc[4][4];
#pragma unroll
    for (int i = 0; i < 4; ++i)
#pragma unroll
        for (int j = 0; j < 4; ++j) acc[i][j] = (f32x4){0.f, 0.f, 0.f, 0.f};

    mfma_gemm_core(aob, Wto, bm, n0, As, Bs, wv, lane, acc);

    const int mb = (wv >> 1) << 6, nb = (wv & 1) << 6;
#pragma unroll
    for (int i = 0; i < 4; ++i) {
        const int m0 = bm + mb + i * 16 + quad * 4;
#pragma unroll
        for (int j = 0; j < 4; ++j) {
            const int n = n0 + nb + j * 16 + m16;
            const float bval = bo[n];
#pragma unroll
            for (int r = 0; r < 4; ++r)
                out[(size_t)(m0 + r) * EMBED + n] = acc[i][j][r] + bval;
        }
    }
}

// ---------------------------------------------------------------------------
// bf16 MFMA flash attention (round-2 kernel, epilogue now writes bf16).
// ---------------------------------------------------------------------------
__global__ __launch_bounds__(256)
void attn_mfma(const unsigned short* __restrict__ Qb,
               const unsigned short* __restrict__ Kb,
               const unsigned short* __restrict__ Vtb,
               unsigned short* __restrict__ Oout)
{
    __shared__ unsigned short Ks[64 * 72];      // [key][d]
    __shared__ unsigned short Vt[64 * 72];      // [d][key]
    __shared__ unsigned short Ps[4][16 * 72];   // per-wave [m][key]

    const int tid  = threadIdx.x;
    const int wv   = tid >> 6;
    const int lane = tid & 63;
    const int m16  = lane & 15;
    const int quad = lane >> 4;
    const int bh   = blockIdx.y;
    const int b    = bh >> 4, h = bh & 15;

    const int srow = tid >> 2;
    const int scol = (tid & 3) << 4;

    for (int phase = 0; phase < 2; ++phase) {
        const int qt = phase == 0 ? (31 - (int)blockIdx.x) : (int)blockIdx.x;
        const int q0 = qt << 6;

        const size_t qoff =
            (((size_t)bh << 11) + q0 + (wv << 4) + m16) * 64 + (quad << 3);
        bf16x8 qa0 = *(const bf16x8*)(Qb + qoff);
        bf16x8 qa1 = *(const bf16x8*)(Qb + qoff + 32);

        f32x4 o[4];
        float m_[4], l_[4];
#pragma unroll
        for (int dt = 0; dt < 4; ++dt) o[dt] = (f32x4){0.f, 0.f, 0.f, 0.f};
#pragma unroll
        for (int r = 0; r < 4; ++r) { m_[r] = -1e30f; l_[r] = 0.f; }

        for (int kt = 0; kt <= qt; ++kt) {
            const int k0 = kt << 6;
            __syncthreads();
            {
                const unsigned short* sk =
                    Kb + (((size_t)bh << 11) + k0 + srow) * 64 + scol;
                *(bf16x8*)(Ks + srow * 72 + scol)     = *(const bf16x8*)(sk);
                *(bf16x8*)(Ks + srow * 72 + scol + 8) = *(const bf16x8*)(sk + 8);
                const unsigned short* sv =
                    Vtb + (((size_t)bh << 6) + srow) * SEQ + k0 + scol;
                *(bf16x8*)(Vt + srow * 72 + scol)     = *(const bf16x8*)(sv);
                *(bf16x8*)(Vt + srow * 72 + scol + 8) = *(const bf16x8*)(sv + 8);
            }
            __syncthreads();

            f32x4 s[4];
#pragma unroll
            for (int g = 0; g < 4; ++g) {
                s[g] = (f32x4){0.f, 0.f, 0.f, 0.f};
                const unsigned short* kp = Ks + (g * 16 + m16) * 72 + (quad << 3);
                bf16x8 kb0 = *(const bf16x8*)kp;
                bf16x8 kb1 = *(const bf16x8*)(kp + 32);
                s[g] = __builtin_amdgcn_mfma_f32_16x16x32_bf16(qa0, kb0, s[g], 0, 0, 0);
                s[g] = __builtin_amdgcn_mfma_f32_16x16x32_bf16(qa1, kb1, s[g], 0, 0, 0);
            }

            if (kt == qt) {
#pragma unroll
                for (int g = 0; g < 4; ++g) {
                    int thr = g * 16 + m16 - wv * 16 - quad * 4;
#pragma unroll
                    for (int r = 0; r < 4; ++r)
                        if (r < thr) s[g][r] = -1e30f;
                }
            }

            float al[4];
#pragma unroll
            for (int r = 0; r < 4; ++r) {
                float v = fmaxf(fmaxf(s[0][r], s[1][r]), fmaxf(s[2][r], s[3][r]));
                v = fmaxf(v, __shfl_xor(v, 1));
                v = fmaxf(v, __shfl_xor(v, 2));
                v = fmaxf(v, __shfl_xor(v, 4));
                v = fmaxf(v, __shfl_xor(v, 8));
                float nm = fmaxf(m_[r], v);
                al[r] = exp2f(m_[r] - nm);
                float sum = 0.f;
#pragma unroll
                for (int g = 0; g < 4; ++g) {
                    float p = exp2f(s[g][r] - nm);
                    s[g][r] = p;
                    sum += p;
                }
                sum += __shfl_xor(sum, 1);
                sum += __shfl_xor(sum, 2);
                sum += __shfl_xor(sum, 4);
                sum += __shfl_xor(sum, 8);
                l_[r] = l_[r] * al[r] + sum;
                m_[r] = nm;
            }

#pragma unroll
            for (int g = 0; g < 4; ++g)
#pragma unroll
                for (int r = 0; r < 4; ++r)
                    Ps[wv][(quad * 4 + r) * 72 + g * 16 + m16] = f2bf(s[g][r]);

#pragma unroll
            for (int dt = 0; dt < 4; ++dt)
#pragma unroll
                for (int r = 0; r < 4; ++r) o[dt][r] *= al[r];

            const unsigned short* pp = &Ps[wv][m16 * 72 + (quad << 3)];
            bf16x8 pa0 = *(const bf16x8*)pp;
            bf16x8 pa1 = *(const bf16x8*)(pp + 32);
#pragma unroll
            for (int dt = 0; dt < 4; ++dt) {
                const unsigned short* vp = Vt + (dt * 16 + m16) * 72 + (quad << 3);
                bf16x8 vb0 = *(const bf16x8*)vp;
                bf16x8 vb1 = *(const bf16x8*)(vp + 32);
                o[dt] = __builtin_amdgcn_mfma_f32_16x16x32_bf16(pa0, vb0, o[dt], 0, 0, 0);
                o[dt] = __builtin_amdgcn_mfma_f32_16x16x32_bf16(pa1, vb1, o[dt], 0, 0, 0);
            }
        }

        float inv[4];
#pragma unroll
        for (int r = 0; r < 4; ++r) inv[r] = 1.f / l_[r];
        const int trow = q0 + (wv << 4) + quad * 4;
#pragma unroll
        for (int dt = 0; dt < 4; ++dt)
#pragma unroll
            for (int r = 0; r < 4; ++r)
                Oout[((size_t)((b << 11) + trow + r) << 10) + (h << 6) + dt * 16 + m16] =
                    f2bf(o[dt][r] * inv[r]);
    }
}

extern "C" void kernel_launch(void* const* d_in, const int* in_sizes, int n_in,
                              void* d_out, int out_size, void* d_ws, size_t ws_size,
                              hipStream_t stream) {
    const float* x  = (const float*)d_in[0];
    const float* Wq = (const float*)d_in[1];
    const float* bq = (const float*)d_in[2];
    const float* Wk = (const float*)d_in[3];
    const float* bk = (const float*)d_in[4];
    const float* Wv = (const float*)d_in[5];
    const float* bv = (const float*)d_in[6];
    const float* Wo = (const float*)d_in[7];
    const float* bo = (const float*)d_in[8];
    float* out = (float*)d_out;

    const size_t HSZ = (size_t)MROWS * EMBED;   // 4M elems
    const size_t WSZ = (size_t)EMBED * EMBED;   // 1M elems
    unsigned short* qb  = (unsigned short*)d_ws;
    unsigned short* kb  = qb + HSZ;
    unsigned short* vtb = kb + HSZ;
    unsigned short* aob = vtb + HSZ;
    unsigned short* xb  = aob + HSZ;
    unsigned short* wtq = xb + HSZ;
    unsigned short* wtk = wtq + WSZ;
    unsigned short* wtv = wtk + WSZ;
    unsigned short* wto = wtv + WSZ;

    cvt_x<<<MROWS * EMBED / 1024, 256, 0, stream>>>(x, xb);
    cvt_w<<<dim3(16, 16, 4), 256, 0, stream>>>(Wq, Wk, Wv, Wo, wtq, wtk, wtv, wto);

    qkv_gemm<<<dim3(24, 32), 256, 0, stream>>>(xb, wtq, wtk, wtv, bq, bk, bv,
                                               qb, kb, vtb);

    attn_mfma<<<dim3(16, BATCH * NHEADS), 256, 0, stream>>>(qb, kb, vtb, aob);

    out_gemm<<<dim3(8, 32), 256, 0, stream>>>(aob, wto, bo, out);
}

// Round 4
// 223.735 us; speedup vs baseline: 6.0196x; 1.1245x over previous
//
#include <hip/hip_runtime.h>

#define EMBED 1024
#define NHEADS 16
#define HDIM 64
#define SEQ 2048
#define BATCH 2
#define MROWS (BATCH * SEQ)   // 4096

using bf16x8 = __attribute__((ext_vector_type(8))) short;
using f32x4  = __attribute__((ext_vector_type(4))) float;
using us4    = __attribute__((ext_vector_type(4))) unsigned short;

__device__ __forceinline__ unsigned short f2bf(float f) {
    unsigned int u = __builtin_bit_cast(unsigned int, f);
    u = (u + 0x7fffu + ((u >> 16) & 1u)) >> 16;   // RNE
    return (unsigned short)u;
}

__device__ __forceinline__ void async16(const unsigned short* g, unsigned short* l) {
    __builtin_amdgcn_global_load_lds(
        (const __attribute__((address_space(1))) void*)g,
        (__attribute__((address_space(3))) void*)l, 16, 0, 0);
}

// ---------------------------------------------------------------------------
// convert x (fp32 [4096][1024]) -> bf16, 4 elems/thread
// ---------------------------------------------------------------------------
__global__ __launch_bounds__(256)
void cvt_x(const float* __restrict__ in, unsigned short* __restrict__ out)
{
    int i = blockIdx.x * 256 + threadIdx.x;
    float4 v = ((const float4*)in)[i];
    us4 o;
    o[0] = f2bf(v.x); o[1] = f2bf(v.y); o[2] = f2bf(v.z); o[3] = f2bf(v.w);
    ((us4*)out)[i] = o;
}

// ---------------------------------------------------------------------------
// convert + transpose weights: W fp32 [k][n] -> Wt bf16 [n][k]. 64x64 tiles.
// ---------------------------------------------------------------------------
__global__ __launch_bounds__(256)
void cvt_w(const float* __restrict__ W0, const float* __restrict__ W1,
           const float* __restrict__ W2, const float* __restrict__ W3,
           unsigned short* __restrict__ T0, unsigned short* __restrict__ T1,
           unsigned short* __restrict__ T2, unsigned short* __restrict__ T3)
{
    const float* W = blockIdx.z == 0 ? W0 : blockIdx.z == 1 ? W1 :
                     blockIdx.z == 2 ? W2 : W3;
    unsigned short* T = blockIdx.z == 0 ? T0 : blockIdx.z == 1 ? T1 :
                        blockIdx.z == 2 ? T2 : T3;
    __shared__ unsigned short tile[64][72];
    const int tid = threadIdx.x;
    const int k0 = blockIdx.y << 6, n0 = blockIdx.x << 6;
    const int lr = tid >> 4, lc = (tid & 15) << 2;
#pragma unroll
    for (int it = 0; it < 4; ++it) {
        int kr = lr + it * 16;
        float4 v = *(const float4*)(W + (size_t)(k0 + kr) * EMBED + n0 + lc);
        tile[lc + 0][kr] = f2bf(v.x);
        tile[lc + 1][kr] = f2bf(v.y);
        tile[lc + 2][kr] = f2bf(v.z);
        tile[lc + 3][kr] = f2bf(v.w);
    }
    __syncthreads();
#pragma unroll
    for (int it = 0; it < 4; ++it) {
        int nr = lr + it * 16;
        us4 o = *(const us4*)(&tile[nr][lc]);
        *(us4*)(T + (size_t)(n0 + nr) * EMBED + k0 + lc) = o;
    }
}

// ---------------------------------------------------------------------------
// MFMA GEMM core 128x128 (unchanged from round 3)
// ---------------------------------------------------------------------------
__device__ __forceinline__ void mfma_gemm_core(
    const unsigned short* __restrict__ A, const unsigned short* __restrict__ Bt,
    int bm, int n0, unsigned short* As, unsigned short* Bs,
    int wv, int lane, f32x4 acc[4][4])
{
    const int m16 = lane & 15, quad = lane >> 4;
    const int mb = (wv >> 1) << 6;
    const int nb = (wv & 1) << 6;

    const unsigned short* ga = A  + (size_t)(bm + wv * 32 + (lane >> 3)) * EMBED + ((lane & 7) << 3);
    const unsigned short* gb = Bt + (size_t)(n0 + wv * 32 + (lane >> 3)) * EMBED + ((lane & 7) << 3);
    unsigned short* la = As + wv * 32 * 64;
    unsigned short* lb = Bs + wv * 32 * 64;

    for (int k0 = 0; k0 < EMBED; k0 += 64) {
        __syncthreads();
#pragma unroll
        for (int j = 0; j < 4; ++j) {
            async16(ga + j * 8 * EMBED, la + j * 8 * 64);
            async16(gb + j * 8 * EMBED, lb + j * 8 * 64);
        }
        ga += 64; gb += 64;
        __syncthreads();
#pragma unroll
        for (int ks = 0; ks < 2; ++ks) {
            const int ko = ks * 32 + (quad << 3);
            bf16x8 af[4], bfv[4];
#pragma unroll
            for (int i = 0; i < 4; ++i) {
                af[i]  = *(const bf16x8*)(As + (mb + i * 16 + m16) * 64 + ko);
                bfv[i] = *(const bf16x8*)(Bs + (nb + i * 16 + m16) * 64 + ko);
            }
#pragma unroll
            for (int i = 0; i < 4; ++i)
#pragma unroll
                for (int j = 0; j < 4; ++j)
                    acc[i][j] = __builtin_amdgcn_mfma_f32_16x16x32_bf16(
                        af[i], bfv[j], acc[i][j], 0, 0, 0);
        }
    }
}

// ---------------------------------------------------------------------------
// MFMA GEMM core 128x64 (for out_gemm: more blocks)
// ---------------------------------------------------------------------------
__device__ __forceinline__ void mfma_gemm_core64(
    const unsigned short* __restrict__ A, const unsigned short* __restrict__ Bt,
    int bm, int n0, unsigned short* As, unsigned short* Bs,
    int wv, int lane, f32x4 acc[4][2])
{
    const int m16 = lane & 15, quad = lane >> 4;
    const int mb = (wv >> 1) << 6;
    const int nb = (wv & 1) << 5;

    const unsigned short* ga = A  + (size_t)(bm + wv * 32 + (lane >> 3)) * EMBED + ((lane & 7) << 3);
    const unsigned short* gb = Bt + (size_t)(n0 + wv * 16 + (lane >> 3)) * EMBED + ((lane & 7) << 3);
    unsigned short* la = As + wv * 32 * 64;
    unsigned short* lb = Bs + wv * 16 * 64;

    for (int k0 = 0; k0 < EMBED; k0 += 64) {
        __syncthreads();
#pragma unroll
        for (int j = 0; j < 4; ++j)
            async16(ga + j * 8 * EMBED, la + j * 8 * 64);
#pragma unroll
        for (int j = 0; j < 2; ++j)
            async16(gb + j * 8 * EMBED, lb + j * 8 * 64);
        ga += 64; gb += 64;
        __syncthreads();
#pragma unroll
        for (int ks = 0; ks < 2; ++ks) {
            const int ko = ks * 32 + (quad << 3);
            bf16x8 af[4], bfv[2];
#pragma unroll
            for (int i = 0; i < 4; ++i)
                af[i] = *(const bf16x8*)(As + (mb + i * 16 + m16) * 64 + ko);
#pragma unroll
            for (int j = 0; j < 2; ++j)
                bfv[j] = *(const bf16x8*)(Bs + (nb + j * 16 + m16) * 64 + ko);
#pragma unroll
            for (int i = 0; i < 4; ++i)
#pragma unroll
                for (int j = 0; j < 2; ++j)
                    acc[i][j] = __builtin_amdgcn_mfma_f32_16x16x32_bf16(
                        af[i], bfv[j], acc[i][j], 0, 0, 0);
        }
    }
}

// ---------------------------------------------------------------------------
// Fused QKV projection (unchanged from round 3)
// ---------------------------------------------------------------------------
__global__ __launch_bounds__(256)
void qkv_gemm(const unsigned short* __restrict__ xb,
              const unsigned short* __restrict__ Wtq,
              const unsigned short* __restrict__ Wtk,
              const unsigned short* __restrict__ Wtv,
              const float* __restrict__ bq, const float* __restrict__ bk,
              const float* __restrict__ bv,
              unsigned short* __restrict__ Qo, unsigned short* __restrict__ Ko,
              unsigned short* __restrict__ Vto)
{
    __shared__ __align__(16) unsigned short As[128 * 64];
    __shared__ __align__(16) unsigned short Bs[128 * 64];
    const int tid = threadIdx.x, wv = tid >> 6, lane = tid & 63;
    const int m16 = lane & 15, quad = lane >> 4;
    const int which = blockIdx.x >> 3;
    const int n0 = (blockIdx.x & 7) << 7;
    const int bm = blockIdx.y << 7;
    const unsigned short* Bt = which == 0 ? Wtq : which == 1 ? Wtk : Wtv;
    const float* bias = which == 0 ? bq : which == 1 ? bk : bv;

    f32x4 acc[4][4];
#pragma unroll
    for (int i = 0; i < 4; ++i)
#pragma unroll
        for (int j = 0; j < 4; ++j) acc[i][j] = (f32x4){0.f, 0.f, 0.f, 0.f};

    mfma_gemm_core(xb, Bt, bm, n0, As, Bs, wv, lane, acc);

    const int mb = (wv >> 1) << 6, nb = (wv & 1) << 6;
    const float qscale = 0.125f * 1.4426950408889634f;
#pragma unroll
    for (int i = 0; i < 4; ++i) {
        const int m0 = bm + mb + i * 16 + quad * 4;
        const int b = m0 >> 11, t0 = m0 & (SEQ - 1);
#pragma unroll
        for (int j = 0; j < 4; ++j) {
            const int n = n0 + nb + j * 16 + m16;
            const int h = n >> 6, d = n & 63;
            const float bval = bias[n];
            if (which == 2) {
                us4 v;
#pragma unroll
                for (int r = 0; r < 4; ++r) v[r] = f2bf(acc[i][j][r] + bval);
                *(us4*)(Vto + ((((size_t)(b * NHEADS + h)) << 6) + d) * SEQ + t0) = v;
            } else {
                const float sc = which == 0 ? qscale : 1.f;
                unsigned short* dst = (which == 0 ? Qo : Ko) +
                    ((((size_t)(b * NHEADS + h)) << 11) + t0) * 64 + d;
#pragma unroll
                for (int r = 0; r < 4; ++r)
                    dst[(size_t)r * 64] = f2bf((acc[i][j][r] + bval) * sc);
            }
        }
    }
}

// ---------------------------------------------------------------------------
// Output projection: out fp32 = ao_bf16 @ Wo + bo. 128x64 tile, 512 blocks.
// ---------------------------------------------------------------------------
__global__ __launch_bounds__(256)
void out_gemm(const unsigned short* __restrict__ aob,
              const unsigned short* __restrict__ Wto,
              const float* __restrict__ bo, float* __restrict__ out)
{
    __shared__ __align__(16) unsigned short As[128 * 64];
    __shared__ __align__(16) unsigned short Bs[64 * 64];
    const int tid = threadIdx.x, wv = tid >> 6, lane = tid & 63;
    const int m16 = lane & 15, quad = lane >> 4;
    const int n0 = blockIdx.x << 6;
    const int bm = blockIdx.y << 7;

    f32x4 acc[4][2];
#pragma unroll
    for (int i = 0; i < 4; ++i)
#pragma unroll
        for (int j = 0; j < 2; ++j) acc[i][j] = (f32x4){0.f, 0.f, 0.f, 0.f};

    mfma_gemm_core64(aob, Wto, bm, n0, As, Bs, wv, lane, acc);

    const int mb = (wv >> 1) << 6, nb = (wv & 1) << 5;
#pragma unroll
    for (int i = 0; i < 4; ++i) {
        const int m0 = bm + mb + i * 16 + quad * 4;
#pragma unroll
        for (int j = 0; j < 2; ++j) {
            const int n = n0 + nb + j * 16 + m16;
            const float bval = bo[n];
#pragma unroll
            for (int r = 0; r < 4; ++r)
                out[(size_t)(m0 + r) * EMBED + n] = acc[i][j][r] + bval;
        }
    }
}

// ---------------------------------------------------------------------------
// bf16 MFMA flash attention, OPERAND-SWAPPED: computes S^T = K·Q^T and
// O^T = V^T·P^T. D's column = query (lane m16), so softmax reduces over the
// 16 in-register scores + 2 cross-quad shuffles (was 32 shuffles). m/l/alpha
// are scalars per lane. Single-barrier ping-pong K/V double buffer with
// register prefetch. Ps stores pack us4; epilogue packs us4.
// ---------------------------------------------------------------------------
__global__ __launch_bounds__(256)
void attn_mfma(const unsigned short* __restrict__ Qb,
               const unsigned short* __restrict__ Kb,
               const unsigned short* __restrict__ Vtb,
               unsigned short* __restrict__ Oout)
{
    __shared__ __align__(16) unsigned short Ks[2][64 * 72];   // [key][d]
    __shared__ __align__(16) unsigned short Vt[2][64 * 72];   // [d][key]
    __shared__ __align__(16) unsigned short Ps[4][16 * 72];   // per-wave [query][key]

    const int tid  = threadIdx.x;
    const int wv   = tid >> 6;
    const int lane = tid & 63;
    const int m16  = lane & 15;
    const int quad = lane >> 4;
    const int bh   = blockIdx.y;
    const int b    = bh >> 4, h = bh & 15;

    const int srow = tid >> 2;         // 0..63
    const int scol = (tid & 3) << 4;   // 0,16,32,48

    bf16x8 rk0, rk1, rv0, rv1;
    auto load_tile = [&](int k0) {
        const unsigned short* sk = Kb + (((size_t)bh << 11) + k0 + srow) * 64 + scol;
        rk0 = *(const bf16x8*)sk;
        rk1 = *(const bf16x8*)(sk + 8);
        const unsigned short* sv = Vtb + (((size_t)bh << 6) + srow) * SEQ + k0 + scol;
        rv0 = *(const bf16x8*)sv;
        rv1 = *(const bf16x8*)(sv + 8);
    };

    for (int phase = 0; phase < 2; ++phase) {
        const int qt = phase == 0 ? (31 - (int)blockIdx.x) : (int)blockIdx.x;
        const int q0 = qt << 6;

        // Q fragment (B operand): lane n = query = m16, k = d
        const size_t qoff =
            (((size_t)bh << 11) + q0 + (wv << 4) + m16) * 64 + (quad << 3);
        bf16x8 qa0 = *(const bf16x8*)(Qb + qoff);
        bf16x8 qa1 = *(const bf16x8*)(Qb + qoff + 32);

        f32x4 o[4];
#pragma unroll
        for (int dt = 0; dt < 4; ++dt) o[dt] = (f32x4){0.f, 0.f, 0.f, 0.f};
        float m_ = -1e30f, l_ = 0.f;

        load_tile(0);
        __syncthreads();   // protect buffers across phases

        for (int kt = 0; kt <= qt; ++kt) {
            unsigned short* Kp = Ks[kt & 1];
            unsigned short* Vp = Vt[kt & 1];
            *(bf16x8*)(Kp + srow * 72 + scol)     = rk0;
            *(bf16x8*)(Kp + srow * 72 + scol + 8) = rk1;
            *(bf16x8*)(Vp + srow * 72 + scol)     = rv0;
            *(bf16x8*)(Vp + srow * 72 + scol + 8) = rv1;
            __syncthreads();
            if (kt < qt) load_tile((kt + 1) << 6);

            const bool diag = (kt == qt);

            // S^T = K·Q^T: D[key=g*16+quad*4+r][query=m16]
            f32x4 s[4];
#pragma unroll
            for (int g = 0; g < 4; ++g) {
                if (diag && g > wv) {
                    s[g] = (f32x4){-1e30f, -1e30f, -1e30f, -1e30f};
                    continue;
                }
                const unsigned short* kp = Kp + (g * 16 + m16) * 72 + (quad << 3);
                bf16x8 kb0 = *(const bf16x8*)kp;
                bf16x8 kb1 = *(const bf16x8*)(kp + 32);
                s[g] = (f32x4){0.f, 0.f, 0.f, 0.f};
                s[g] = __builtin_amdgcn_mfma_f32_16x16x32_bf16(kb0, qa0, s[g], 0, 0, 0);
                s[g] = __builtin_amdgcn_mfma_f32_16x16x32_bf16(kb1, qa1, s[g], 0, 0, 0);
            }
            if (diag) {
                // only g==wv is partially masked (g<wv fully unmasked, g>wv filled)
#pragma unroll
                for (int r = 0; r < 4; ++r)
                    if (quad * 4 + r > m16) s[wv][r] = -1e30f;
            }

            // online softmax: all 16 scores belong to query m16
            float mx = s[0][0];
#pragma unroll
            for (int g = 0; g < 4; ++g)
#pragma unroll
                for (int r = 0; r < 4; ++r) mx = fmaxf(mx, s[g][r]);
            mx = fmaxf(mx, __shfl_xor(mx, 16));
            mx = fmaxf(mx, __shfl_xor(mx, 32));
            const float nm = fmaxf(m_, mx);
            const float alpha = exp2f(m_ - nm);
            float sum = 0.f;
#pragma unroll
            for (int g = 0; g < 4; ++g)
#pragma unroll
                for (int r = 0; r < 4; ++r) {
                    float p = exp2f(s[g][r] - nm);
                    s[g][r] = p;
                    sum += p;
                }
            sum += __shfl_xor(sum, 16);
            sum += __shfl_xor(sum, 32);
            l_ = l_ * alpha + sum;
            m_ = nm;

            // P^T -> Ps[query][key], us4-packed (keys quad*4+r contiguous)
#pragma unroll
            for (int g = 0; g < 4; ++g) {
                us4 pv;
#pragma unroll
                for (int r = 0; r < 4; ++r) pv[r] = f2bf(s[g][r]);
                *(us4*)(&Ps[wv][m16 * 72 + g * 16 + quad * 4]) = pv;
            }

#pragma unroll
            for (int dt = 0; dt < 4; ++dt) o[dt] *= alpha;

            // O^T += V^T·P^T: A = V^T-frag, B = P^T-frag
            const unsigned short* pp = &Ps[wv][m16 * 72 + (quad << 3)];
            bf16x8 pa0 = *(const bf16x8*)pp;
            bf16x8 pa1 = *(const bf16x8*)(pp + 32);
            const bool skip_hi = diag && (wv < 2);   // keys 32..63 all masked
#pragma unroll
            for (int dt = 0; dt < 4; ++dt) {
                const unsigned short* vp = Vp + (dt * 16 + m16) * 72 + (quad << 3);
                bf16x8 vb0 = *(const bf16x8*)vp;
                o[dt] = __builtin_amdgcn_mfma_f32_16x16x32_bf16(vb0, pa0, o[dt], 0, 0, 0);
                if (!skip_hi) {
                    bf16x8 vb1 = *(const bf16x8*)(vp + 32);
                    o[dt] = __builtin_amdgcn_mfma_f32_16x16x32_bf16(vb1, pa1, o[dt], 0, 0, 0);
                }
            }
        }

        // epilogue: lane m16 = query t, holds d = dt*16 + quad*4 + r
        const float inv = 1.f / l_;
        const int t = q0 + (wv << 4) + m16;
        unsigned short* dst =
            Oout + ((size_t)((b << 11) + t) << 10) + (h << 6) + (quad << 2);
#pragma unroll
        for (int dt = 0; dt < 4; ++dt) {
            us4 w;
#pragma unroll
            for (int r = 0; r < 4; ++r) w[r] = f2bf(o[dt][r] * inv);
            *(us4*)(dst + dt * 16) = w;
        }
    }
}

extern "C" void kernel_launch(void* const* d_in, const int* in_sizes, int n_in,
                              void* d_out, int out_size, void* d_ws, size_t ws_size,
                              hipStream_t stream) {
    const float* x  = (const float*)d_in[0];
    const float* Wq = (const float*)d_in[1];
    const float* bq = (const float*)d_in[2];
    const float* Wk = (const float*)d_in[3];
    const float* bk = (const float*)d_in[4];
    const float* Wv = (const float*)d_in[5];
    const float* bv = (const float*)d_in[6];
    const float* Wo = (const float*)d_in[7];
    const float* bo = (const float*)d_in[8];
    float* out = (float*)d_out;

    const size_t HSZ = (size_t)MROWS * EMBED;   // 4M elems
    const size_t WSZ = (size_t)EMBED * EMBED;   // 1M elems
    unsigned short* qb  = (unsigned short*)d_ws;
    unsigned short* kb  = qb + HSZ;
    unsigned short* vtb = kb + HSZ;
    unsigned short* aob = vtb + HSZ;
    unsigned short* xb  = aob + HSZ;
    unsigned short* wtq = xb + HSZ;
    unsigned short* wtk = wtq + WSZ;
    unsigned short* wtv = wtk + WSZ;
    unsigned short* wto = wtv + WSZ;

    cvt_x<<<MROWS * EMBED / 1024, 256, 0, stream>>>(x, xb);
    cvt_w<<<dim3(16, 16, 4), 256, 0, stream>>>(Wq, Wk, Wv, Wo, wtq, wtk, wtv, wto);

    qkv_gemm<<<dim3(24, 32), 256, 0, stream>>>(xb, wtq, wtk, wtv, bq, bk, bv,
                                               qb, kb, vtb);

    attn_mfma<<<dim3(16, BATCH * NHEADS), 256, 0, stream>>>(qb, kb, vtb, aob);

    out_gemm<<<dim3(16, 32), 256, 0, stream>>>(aob, wto, bo, out);
}